// Round 2
// baseline (360.716 us; speedup 1.0000x reference)
//
#include <hip/hip_runtime.h>
#include <hip/hip_bf16.h>

// Net_22625887715641: fused conv-feats + channel-normalize + 32x32 normalized
// cross-correlation (23x23 shifts, 362x362 templates).
//
// R12 vs R11 (corr 170us, MfmaUtil 40.6%, Occupancy 26.4%):
//  Diagnosis: no throughput wall (LDS pipe ~27%, L2 ~15%, HBM 0.5%); the
//  60% non-MFMA time is latency exposure at 12 waves/CU (2 blocks). R11's
//  reg diet landed at exactly 96 unified regs (48 VGPR + 48 AGPR acc) ->
//  5 waves/SIMD fit (5x96=480<=512), so THREE 6-wave blocks/CU are
//  resident-capable (18 waves, SIMDs 5,5,4,4; LDS 3x27.6KB=83KB<=160KB).
//  R10 missed this at 100 regs (rounds past 96), hence its 1.5 rounds.
//  - NCHUNKS 16 -> 24: grid = 32*24 = 768 = exactly 3 blocks/CU, single
//    round at 18 waves/CU. 24%8==0 keeps chunk%8 XCD L2 locality.
//  - corr codegen otherwise identical (same launch_bounds, same loops):
//    clean A/B on residency.
//  - feat/pack/prep unchanged.

typedef unsigned short ushort_t;
typedef unsigned int uint_t;
typedef unsigned char uchar_t;
typedef __attribute__((ext_vector_type(4))) float f32x4;
typedef __attribute__((ext_vector_type(16))) float f32x16;
typedef __attribute__((ext_vector_type(4))) uint_t uint4_t;
typedef __attribute__((ext_vector_type(2))) uint_t uint2_t;

#define EPSF 2.2204460492503131e-16f
#define X1_N (32*384*384)
#define X2_N (32*32*23*23)

// filtb: fp8 [372 rows][48 xb][32 o][8 j]; row = yf+5 (data rows 5..366)
#define FILTB_BYTES (372*48*32*8)
// prevb: fp8 [32 c][385 rows][432 x]; data rows 0..383 cols 0..383; zeros else
#define PREVB_STRIDE 432
#define PREVB_BYTES (32*385*PREVB_STRIDE)
#define ZERO_BYTES ((size_t)FILTB_BYTES + PREVB_BYTES)
// fT2: fp32 [16 chp][45 rows][12] after prevb
#define FT2_ELEMS (16*45*12)

#define YMAX 367            // y-steps 0..366
#define NCHUNKS 24          // 32*24 = 768 blocks = exactly 3/CU, one round
#define INV_AREA (1.0f/131044.0f)

// sB bytes: [dyb 4][copy 8][432]; copy stride 432 (16-mult, 48B bank stagger)
#define SB_COPY_B 432
#define SB_DYB_B  (8*SB_COPY_B)     // 3456
#define SB_BYTES  (4*SB_DYB_B)      // 13824 B per buffer; x2 double-buffer

// ---------------------------------------------------------------------------
// fp32 -> fp8 e4m3 (OCP), RNE, input assumed in [0, 448).
// ---------------------------------------------------------------------------
__device__ __forceinline__ uint_t f32_to_e4m3(float f) {
  if (f < 0.015625f)                         // subnormal: m * 2^-9
    return (uint_t)__float2int_rn(f * 512.0f);
  uint_t b = __builtin_bit_cast(uint_t, f);
  int e = (int)(b >> 23) - 127;
  uint_t m = b & 0x7FFFFFu;
  uint_t keep = m >> 20;
  uint_t rest = m & 0xFFFFFu;
  keep += (rest > 0x80000u) || (rest == 0x80000u && (keep & 1u));
  if (keep == 8u) { keep = 0u; e += 1; }
  if (e > 8) return 0x7Eu;                   // saturate 448
  return (uint_t)(((e + 7) << 3) | keep);
}

// ---------------------------------------------------------------------------
// Prep: pack filters to [chp][45][12] (rows 16B-aligned, b-contiguous).
// ---------------------------------------------------------------------------
__global__ void prep_kernel(const float* __restrict__ ft, const float* __restrict__ fn,
                            float* __restrict__ fT2)
{
  const int e = blockIdx.x * 256 + threadIdx.x;
  if (e < FT2_ELEMS) {
    const int chp = e / 540;
    const int rem = e - chp * 540;
    const int row = rem / 12;
    const int j = rem - row * 12;
    float v = 0.f;
    if (j < 11) {
      if (row < 33)      v = ft[chp * 363 + row * 11 + j];        // row = t*11+a
      else if (row < 44) v = fn[chp * 121 + (row - 33) * 11 + j]; // row-33 = a
    }
    fT2[e] = v;
  }
}

// ---------------------------------------------------------------------------
// Stage 1: thread = (ch-pair chp) x (16-px row). Block 128 = 8 rows x 16 chp.
// mode 0: x -> x1 (fp32). mode 1: xprev -> prevb (fp8 e4m3).
// ---------------------------------------------------------------------------
__global__ __launch_bounds__(128, 4) void feat_kernel(
    const float* __restrict__ xcur, const float* __restrict__ xprev,
    const float* __restrict__ fT2,
    float* __restrict__ out_x1, uchar_t* __restrict__ prevb)
{
  __shared__ float sPx[3 * 18 * 28];
  const int tid = threadIdx.x;
  const int chp = tid & 15;
  const int r = tid >> 4;              // 0..7
  const int j0 = blockIdx.x * 16;
  const int i0 = blockIdx.y * 8;
  const int i = i0 + r;
  const int mode = blockIdx.z;
  const float* __restrict__ xin = mode ? xprev : xcur;

  for (int e = tid; e < 3 * 18 * 26; e += 128) {
    const int t = e / 468;
    const int rem = e - t * 468;
    const int ri = rem / 26;
    const int ci = rem - ri * 26;
    sPx[(t * 18 + ri) * 28 + ci] = xin[((size_t)t * 394 + i0 + ri) * 394 + j0 + ci];
  }
  __syncthreads();

  const float* __restrict__ fbase = fT2 + chp * 540;

  float accT[16], accN[16];
#pragma unroll
  for (int p = 0; p < 16; ++p) { accT[p] = 0.f; accN[p] = 0.f; }

#pragma unroll
  for (int t = 0; t < 3; ++t) {
    for (int a = 0; a < 11; ++a) {
      const float* row = &sPx[(t * 18 + r + a) * 28];
      float wv[26];
#pragma unroll
      for (int k = 0; k < 6; ++k) {
        const f32x4 q = *(const f32x4*)(row + 4 * k);
        wv[4 * k + 0] = q[0]; wv[4 * k + 1] = q[1];
        wv[4 * k + 2] = q[2]; wv[4 * k + 3] = q[3];
      }
      wv[24] = row[24]; wv[25] = row[25];

      const float* fr = fbase + (t * 11 + a) * 12;
      const f32x4 fq0 = *(const f32x4*)(fr);
      const f32x4 fq1 = *(const f32x4*)(fr + 4);
      const f32x4 fq2 = *(const f32x4*)(fr + 8);
      float fv[12];
#pragma unroll
      for (int k = 0; k < 4; ++k) { fv[k] = fq0[k]; fv[4+k] = fq1[k]; fv[8+k] = fq2[k]; }
      float fv2[12];
      if (t == 2) {
        const float* fr2 = fbase + (33 + a) * 12;
        const f32x4 g0 = *(const f32x4*)(fr2);
        const f32x4 g1 = *(const f32x4*)(fr2 + 4);
        const f32x4 g2 = *(const f32x4*)(fr2 + 8);
#pragma unroll
        for (int k = 0; k < 4; ++k) { fv2[k] = g0[k]; fv2[4+k] = g1[k]; fv2[8+k] = g2[k]; }
      }

#pragma unroll
      for (int b = 0; b < 11; ++b) {
        const float fT = fv[b];
#pragma unroll
        for (int p = 0; p < 16; ++p) accT[p] = fmaf(wv[b + p], fT, accT[p]);
        if (t == 2) {
          const float fN = fv2[b];
#pragma unroll
          for (int p = 0; p < 16; ++p) accN[p] = fmaf(wv[b + p], fN, accN[p]);
        }
      }
    }
  }

  float o0[16], o1[16];
#pragma unroll
  for (int p = 0; p < 16; ++p) {
    const float vT = fmaxf(accT[p], 0.f) * 0.5f;   // temp: relu(conv)/2
    const float vN = fmaxf(accN[p], 0.f);
    float s = vT + vN;
    s += __shfl_xor(s, 1);  s += __shfl_xor(s, 2);
    s += __shfl_xor(s, 4);  s += __shfl_xor(s, 8);
    const float inv = 1.f / (s + EPSF);
    o0[p] = vT * inv;
    o1[p] = vN * inv;
  }

  if (mode == 0) {
#pragma unroll
    for (int q = 0; q < 4; ++q) {
      f32x4 v0 = {o0[4*q], o0[4*q+1], o0[4*q+2], o0[4*q+3]};
      f32x4 v1 = {o1[4*q], o1[4*q+1], o1[4*q+2], o1[4*q+3]};
      *(f32x4*)(out_x1 + (size_t)chp * 147456 + i * 384 + j0 + 4 * q) = v0;
      *(f32x4*)(out_x1 + (size_t)(chp + 16) * 147456 + i * 384 + j0 + 4 * q) = v1;
    }
  } else {
    uint4_t u0, u1;
#pragma unroll
    for (int q = 0; q < 4; ++q) {
      u0[q] = f32_to_e4m3(o0[4*q]) | (f32_to_e4m3(o0[4*q+1]) << 8) |
              (f32_to_e4m3(o0[4*q+2]) << 16) | (f32_to_e4m3(o0[4*q+3]) << 24);
      u1[q] = f32_to_e4m3(o1[4*q]) | (f32_to_e4m3(o1[4*q+1]) << 8) |
              (f32_to_e4m3(o1[4*q+2]) << 16) | (f32_to_e4m3(o1[4*q+3]) << 24);
    }
    *(uint4_t*)(prevb + ((size_t)chp * 385 + i) * PREVB_STRIDE + j0) = u0;
    *(uint4_t*)(prevb + ((size_t)(chp + 16) * 385 + i) * PREVB_STRIDE + j0) = u1;
  }
}

// ---------------------------------------------------------------------------
// Pack x1 (fp32, cropped) into filtb fp8 MFMA-A layout; coalesced 8B writes.
// ---------------------------------------------------------------------------
__global__ __launch_bounds__(256) void pack_kernel(
    const float* __restrict__ x1, uchar_t* __restrict__ filtb)
{
  const int e = blockIdx.x * 256 + threadIdx.x;
  if (e >= 362 * 46 * 32) return;
  const int o = e & 31;
  const int q = e >> 5;
  const int xb = q % 46;
  const int rowr = q / 46 + 5;          // 5..366
  const int i = rowr + 6;               // 11..372
  const int j0 = 11 + xb * 8;
  const float* src = x1 + (size_t)o * 147456 + i * 384 + j0;
  uint_t w0 = 0, w1 = 0;
#pragma unroll
  for (int k = 0; k < 4; ++k) {
    w0 |= f32_to_e4m3((j0 + k     <= 372) ? src[k]     : 0.f) << (8 * k);
    w1 |= f32_to_e4m3((j0 + 4 + k <= 372) ? src[4 + k] : 0.f) << (8 * k);
  }
  uint2_t u = {w0, w1};
  *(uint2_t*)(filtb + (((size_t)(rowr * 48 + xb) * 32 + o) << 3)) = u;
}

// ---------------------------------------------------------------------------
// Stage 2: correlation via 32x32x16 fp8 MFMA.
//   out[o,c,dy,dx] = sum_{y,x} filt[o][y-dy_a][x] * prev[c][y+6*dy_b][x+dx]
//   M=192=(dy_a 6)x(o 32); N=96: n = dyb*24+dx (dx 0..22, 23=pad); K=(y, x).
// Block 384 thr = 6 waves, ONE channel; wave w = dy_a w, all 3 N-tiles of 32.
// A-operand row = y-w+5 is WAVE-UNIFORM -> one coalesced 8B load/lane/Kt.
// Operand map (32x32x16): m/n = lane&31, k = (lane>>5)*8 + j.
// C/D map: col = lane&31, row = (reg&3)+8*(reg>>2)+4*(lane>>5).
// Double-buffered sB: stage y+1 while computing y; one barrier per y.
// 96 unified regs (48V+48A) -> 5 waves/SIMD -> 3 blocks/CU resident.
// ---------------------------------------------------------------------------
__global__ __launch_bounds__(384, 4) void corr_kernel(
    const uchar_t* __restrict__ filtb, const uchar_t* __restrict__ prevb,
    float* __restrict__ x2)
{
  __shared__ uint_t sB[2 * (SB_BYTES / 4)];    // 27648 B

  const int tid = threadIdx.x;
  const int lane = tid & 63;
  const int w = tid >> 6;                // 0..5 = dy_a
  const int kg = lane >> 5;              // k-group 0..1
  const int nn = lane & 31;              // n (or o) within tile

  const int ch = blockIdx.x / NCHUNKS;         // 0..31
  const int chunk = blockIdx.x % NCHUNKS;      // 0..23; %8 == XCD
  const int y0 = (chunk * YMAX) / NCHUNKS;     // balanced 15-16 y-steps
  const int y1 = ((chunk + 1) * YMAX) / NCHUNKS;

  // Per-lane B-fragment byte offsets (Kt*16 added at use). All 8B-aligned.
  int boffB[3];
#pragma unroll
  for (int nt = 0; nt < 3; ++nt) {
    const int n = nt * 32 + nn;          // 0..95
    const int dyb = n / 24;
    const int dxr = n - 24 * dyb;
    const int dx = (dxr < 23) ? dxr : 22;      // pad lane reads valid data
    const int s = dx & 7;
    boffB[nt] = dyb * SB_DYB_B + s * SB_COPY_B + (dx >> 3) * 8 + kg * 8;
  }

  // Staging: 104 tasks (dyb = t/26, 16B group g = t%26); 24B src window each.
  const bool st_act = (tid < 104);
  const int sdyb = st_act ? (tid / 26) : 0;
  const int sg = tid - 26 * (st_act ? (tid / 26) : 0);
  const uchar_t* srcbase = prevb + ((size_t)(ch * 385 + 6 * sdyb)) * PREVB_STRIDE;
  const int dstoff = sdyb * (SB_DYB_B / 4) + 4 * sg;   // word offset in buffer

  uint_t st0 = 0, st1 = 0, st2 = 0, st3 = 0, st4 = 0, st5 = 0;

  // load prevb row for y-step yy into st regs
  auto load_st = [&](int yy) {
    const uint_t* sw = (const uint_t*)(srcbase + (size_t)yy * PREVB_STRIDE) + 4 * sg;
    const uint4_t lo = *(const uint4_t*)(sw);
    const uint2_t hi = *(const uint2_t*)(sw + 4);
    st0 = lo.x; st1 = lo.y; st2 = lo.z; st3 = lo.w; st4 = hi.x; st5 = hi.y;
  };

  // expand st regs into 8 byte-shifted copies in buffer buf
  auto write_shift = [&](int buf) {
    uint_t* dst = sB + buf * (SB_BYTES / 4) + dstoff;
    const uint_t wd[6] = {st0, st1, st2, st3, st4, st5};
#pragma unroll
    for (int s = 0; s < 8; ++s) {
      const int off = s >> 2;
      const int b = (s & 3) * 8;
      uint4_t v;
      if (b == 0) {
        v = uint4_t{wd[off], wd[off + 1], wd[off + 2], wd[off + 3]};
      } else {
        v = uint4_t{(wd[off]     >> b) | (wd[off + 1] << (32 - b)),
                    (wd[off + 1] >> b) | (wd[off + 2] << (32 - b)),
                    (wd[off + 2] >> b) | (wd[off + 3] << (32 - b)),
                    (wd[off + 3] >> b) | (wd[off + 4] << (32 - b))};
      }
      *(uint4_t*)(dst + s * (SB_COPY_B / 4)) = v;
    }
  };

  f32x16 acc[3];
#pragma unroll
  for (int nt = 0; nt < 3; ++nt)
#pragma unroll
    for (int r = 0; r < 16; ++r) acc[nt][r] = 0.f;

  // Prologue: stage y0 into buf 0; preload y0+1 into regs.
  if (st_act) {
    load_st(y0);
    write_shift(0);
    if (y0 + 1 < y1) load_st(y0 + 1);
  }

  // A stream: rows are contiguous in filtb (row stride 12288 = 24 Kt * 512B),
  // so Af0/Af1 roll across y-iterations without re-warm.
  const uchar_t* aptr = filtb + (size_t)(y0 - w + 5) * 12288 + kg * 256 + nn * 8;
  long Af0 = *(const long*)(aptr);
  long Af1 = *(const long*)(aptr + 512);

  __syncthreads();                       // buf0 staged

  for (int y = y0; y < y1; ++y) {
    const int pb = (y - y0) & 1;         // buffer being read this iteration

    // Stage y+1 into the other buffer (read during y-1; all waves passed the
    // end-of-(y-1) barrier, so it's free). Then prefetch y+2 into regs —
    // a full K-loop of latency cover.
    if (st_act && y + 1 < y1) write_shift(pb ^ 1);
    if (st_act && y + 2 < y1) load_st(y + 2);

    const char* sBrd = (const char*)sB + pb * SB_BYTES;

    // K-loop: 24 Kt16 steps; A prefetched 2 deep (rolling, unclamped), B 1 deep.
    long Af2, Bf[3], Bfn[3];
#pragma unroll
    for (int nt = 0; nt < 3; ++nt)
      Bf[nt] = *(const long*)(sBrd + boffB[nt]);

#pragma unroll
    for (int Kt = 0; Kt < 24; ++Kt) {
      Af2 = *(const long*)(aptr + ((Kt + 2) << 9));   // rolls into next row
      const int Ktb = (Kt + 1 < 24) ? Kt + 1 : 23;
#pragma unroll
      for (int nt = 0; nt < 3; ++nt)
        Bfn[nt] = *(const long*)(sBrd + boffB[nt] + (Ktb << 4));
#pragma unroll
      for (int nt = 0; nt < 3; ++nt)
        acc[nt] = __builtin_amdgcn_mfma_f32_32x32x16_fp8_fp8(
            Af0, Bf[nt], acc[nt], 0, 0, 0);
      Af0 = Af1; Af1 = Af2;
#pragma unroll
      for (int nt = 0; nt < 3; ++nt) Bf[nt] = Bfn[nt];
    }
    aptr += 12288;                       // next y: row += 1 (Af0/Af1 now hold it)

    __syncthreads();                     // staging y+1 visible; reads of pb done
  }

  // Epilogue: scale partials, atomically accumulate into x2[o][c][dy][dx].
#pragma unroll
  for (int nt = 0; nt < 3; ++nt) {
    const int n = nt * 32 + nn;
    const int dyb = n / 24;
    const int dxr = n - 24 * dyb;
    if (dxr < 23) {
      const int dy = w + 6 * dyb;
      if (dy <= 22) {
#pragma unroll
        for (int r = 0; r < 16; ++r) {
          const int o = (r & 3) + 8 * (r >> 2) + 4 * kg;   // C/D row
          atomicAdd(&x2[((o * 32 + ch) * 23 + dy) * 23 + dxr],
                    acc[nt][r] * INV_AREA);
        }
      }
    }
  }
}

// ---------------------------------------------------------------------------
extern "C" void kernel_launch(void* const* d_in, const int* in_sizes, int n_in,
                              void* d_out, int out_size, void* d_ws, size_t ws_size,
                              hipStream_t stream)
{
  const float* x     = (const float*)d_in[0];   // [3][394][394]
  const float* xprev = (const float*)d_in[1];
  const float* ft    = (const float*)d_in[2];   // [16][3][11][11]
  const float* fn    = (const float*)d_in[3];   // [16][1][11][11]
  float* out = (float*)d_out;

  uchar_t* filtb = (uchar_t*)d_ws;
  uchar_t* prevb = filtb + FILTB_BYTES;
  float* fT2 = (float*)(prevb + PREVB_BYTES);

  // Zero packed buffers (zero padding) and the x2 accumulator.
  hipMemsetAsync(d_ws, 0, ZERO_BYTES, stream);
  hipMemsetAsync(out + X1_N, 0, (size_t)X2_N * sizeof(float), stream);

  prep_kernel<<<dim3((FT2_ELEMS + 255) / 256), 256, 0, stream>>>(ft, fn, fT2);
  feat_kernel<<<dim3(24, 48, 2), 128, 0, stream>>>(x, xprev, fT2, out, prevb);
  pack_kernel<<<dim3((362 * 46 * 32 + 255) / 256), 256, 0, stream>>>(out, filtb);
  corr_kernel<<<dim3(32 * NCHUNKS), 384, 0, stream>>>(filtb, prevb, out + X1_N);
}

// Round 3
// 325.133 us; speedup vs baseline: 1.1094x; 1.1094x over previous
//
#include <hip/hip_runtime.h>
#include <hip/hip_bf16.h>

// Net_22625887715641: fused conv-feats + channel-normalize + 32x32 normalized
// cross-correlation (23x23 shifts, 362x362 templates).
//
// R13 vs R12 (corr 222us REGRESSION) / R11 (corr 170us, MfmaUtil 40.6%):
//  R12 post-mortem: 3 blocks/CU never resident. A 6-wave block places
//  2,2,1,1 waves on the 4 SIMDs; two blocks -> 4,4,2,2; a third needs 6
//  waves on SIMD0/1 = 6x96 regs = 576 > 512. 6-wave blocks cap at 2/CU.
//  -> revert NCHUNKS to 16 (R11 config, exactly 2 blocks/CU, one round).
//  R11 residual: no throughput wall (MFMA 6.9k / LDS ~6k / L1 ~2.3k cyc
//  per CU-y-step vs 17.7k wall). Exposure = per-y barrier convoy: 23
//  joins/block where waves 2-5 idle behind waves 0-1's staging chain,
//  then all burst-restart. Fix:
//  - Stage TWO y-rows per buffer: sB = 2 buf x 2 rows x 13824B = 55296B
//    (<=64KB static; 2 blocks = 110KB <= 160KB/CU). K-loop = 48 Kt per
//    barrier; A rows contiguous in filtb so rolling A prefetch crosses
//    the row boundary for free; B sub-row switch at Kt=24 is a
//    compile-time offset. Barriers/block: 23 -> 11-12.
//  - Staging tasks 104 -> 208 (2 rows), spread over waves 0-3: halves
//    per-wave staging critical path at the join.
//  - Odd y-count: 24-Kt tail loop on the already-staged row.
//  - feat/pack/prep unchanged.

typedef unsigned short ushort_t;
typedef unsigned int uint_t;
typedef unsigned char uchar_t;
typedef __attribute__((ext_vector_type(4))) float f32x4;
typedef __attribute__((ext_vector_type(16))) float f32x16;
typedef __attribute__((ext_vector_type(4))) uint_t uint4_t;
typedef __attribute__((ext_vector_type(2))) uint_t uint2_t;

#define EPSF 2.2204460492503131e-16f
#define X1_N (32*384*384)
#define X2_N (32*32*23*23)

// filtb: fp8 [372 rows][48 xb][32 o][8 j]; row = yf+5 (data rows 5..366)
#define FILTB_BYTES (372*48*32*8)
// prevb: fp8 [32 c][385 rows][432 x]; data rows 0..383 cols 0..383; zeros else
#define PREVB_STRIDE 432
#define PREVB_BYTES (32*385*PREVB_STRIDE)
#define ZERO_BYTES ((size_t)FILTB_BYTES + PREVB_BYTES)
// fT2: fp32 [16 chp][45 rows][12] after prevb
#define FT2_ELEMS (16*45*12)

#define YMAX 367            // y-steps 0..366
#define NCHUNKS 16          // 32*16 = 512 blocks = exactly 2/CU, one round
#define INV_AREA (1.0f/131044.0f)

// One y-row image in LDS: [dyb 4][copy 8][432]; copy stride 432
#define SB_COPY_B 432
#define SB_DYB_B  (8*SB_COPY_B)     // 3456
#define SB_ROW_B  (4*SB_DYB_B)      // 13824 B per y-row
#define SB_BUF_B  (2*SB_ROW_B)      // 27648 B per pair-buffer (2 y-rows)
#define SB_TOT_B  (2*SB_BUF_B)      // 55296 B total (double-buffered pairs)

// ---------------------------------------------------------------------------
// fp32 -> fp8 e4m3 (OCP), RNE, input assumed in [0, 448).
// ---------------------------------------------------------------------------
__device__ __forceinline__ uint_t f32_to_e4m3(float f) {
  if (f < 0.015625f)                         // subnormal: m * 2^-9
    return (uint_t)__float2int_rn(f * 512.0f);
  uint_t b = __builtin_bit_cast(uint_t, f);
  int e = (int)(b >> 23) - 127;
  uint_t m = b & 0x7FFFFFu;
  uint_t keep = m >> 20;
  uint_t rest = m & 0xFFFFFu;
  keep += (rest > 0x80000u) || (rest == 0x80000u && (keep & 1u));
  if (keep == 8u) { keep = 0u; e += 1; }
  if (e > 8) return 0x7Eu;                   // saturate 448
  return (uint_t)(((e + 7) << 3) | keep);
}

// ---------------------------------------------------------------------------
// Prep: pack filters to [chp][45][12] (rows 16B-aligned, b-contiguous).
// ---------------------------------------------------------------------------
__global__ void prep_kernel(const float* __restrict__ ft, const float* __restrict__ fn,
                            float* __restrict__ fT2)
{
  const int e = blockIdx.x * 256 + threadIdx.x;
  if (e < FT2_ELEMS) {
    const int chp = e / 540;
    const int rem = e - chp * 540;
    const int row = rem / 12;
    const int j = rem - row * 12;
    float v = 0.f;
    if (j < 11) {
      if (row < 33)      v = ft[chp * 363 + row * 11 + j];        // row = t*11+a
      else if (row < 44) v = fn[chp * 121 + (row - 33) * 11 + j]; // row-33 = a
    }
    fT2[e] = v;
  }
}

// ---------------------------------------------------------------------------
// Stage 1: thread = (ch-pair chp) x (16-px row). Block 128 = 8 rows x 16 chp.
// mode 0: x -> x1 (fp32). mode 1: xprev -> prevb (fp8 e4m3).
// ---------------------------------------------------------------------------
__global__ __launch_bounds__(128, 4) void feat_kernel(
    const float* __restrict__ xcur, const float* __restrict__ xprev,
    const float* __restrict__ fT2,
    float* __restrict__ out_x1, uchar_t* __restrict__ prevb)
{
  __shared__ float sPx[3 * 18 * 28];
  const int tid = threadIdx.x;
  const int chp = tid & 15;
  const int r = tid >> 4;              // 0..7
  const int j0 = blockIdx.x * 16;
  const int i0 = blockIdx.y * 8;
  const int i = i0 + r;
  const int mode = blockIdx.z;
  const float* __restrict__ xin = mode ? xprev : xcur;

  for (int e = tid; e < 3 * 18 * 26; e += 128) {
    const int t = e / 468;
    const int rem = e - t * 468;
    const int ri = rem / 26;
    const int ci = rem - ri * 26;
    sPx[(t * 18 + ri) * 28 + ci] = xin[((size_t)t * 394 + i0 + ri) * 394 + j0 + ci];
  }
  __syncthreads();

  const float* __restrict__ fbase = fT2 + chp * 540;

  float accT[16], accN[16];
#pragma unroll
  for (int p = 0; p < 16; ++p) { accT[p] = 0.f; accN[p] = 0.f; }

#pragma unroll
  for (int t = 0; t < 3; ++t) {
    for (int a = 0; a < 11; ++a) {
      const float* row = &sPx[(t * 18 + r + a) * 28];
      float wv[26];
#pragma unroll
      for (int k = 0; k < 6; ++k) {
        const f32x4 q = *(const f32x4*)(row + 4 * k);
        wv[4 * k + 0] = q[0]; wv[4 * k + 1] = q[1];
        wv[4 * k + 2] = q[2]; wv[4 * k + 3] = q[3];
      }
      wv[24] = row[24]; wv[25] = row[25];

      const float* fr = fbase + (t * 11 + a) * 12;
      const f32x4 fq0 = *(const f32x4*)(fr);
      const f32x4 fq1 = *(const f32x4*)(fr + 4);
      const f32x4 fq2 = *(const f32x4*)(fr + 8);
      float fv[12];
#pragma unroll
      for (int k = 0; k < 4; ++k) { fv[k] = fq0[k]; fv[4+k] = fq1[k]; fv[8+k] = fq2[k]; }
      float fv2[12];
      if (t == 2) {
        const float* fr2 = fbase + (33 + a) * 12;
        const f32x4 g0 = *(const f32x4*)(fr2);
        const f32x4 g1 = *(const f32x4*)(fr2 + 4);
        const f32x4 g2 = *(const f32x4*)(fr2 + 8);
#pragma unroll
        for (int k = 0; k < 4; ++k) { fv2[k] = g0[k]; fv2[4+k] = g1[k]; fv2[8+k] = g2[k]; }
      }

#pragma unroll
      for (int b = 0; b < 11; ++b) {
        const float fT = fv[b];
#pragma unroll
        for (int p = 0; p < 16; ++p) accT[p] = fmaf(wv[b + p], fT, accT[p]);
        if (t == 2) {
          const float fN = fv2[b];
#pragma unroll
          for (int p = 0; p < 16; ++p) accN[p] = fmaf(wv[b + p], fN, accN[p]);
        }
      }
    }
  }

  float o0[16], o1[16];
#pragma unroll
  for (int p = 0; p < 16; ++p) {
    const float vT = fmaxf(accT[p], 0.f) * 0.5f;   // temp: relu(conv)/2
    const float vN = fmaxf(accN[p], 0.f);
    float s = vT + vN;
    s += __shfl_xor(s, 1);  s += __shfl_xor(s, 2);
    s += __shfl_xor(s, 4);  s += __shfl_xor(s, 8);
    const float inv = 1.f / (s + EPSF);
    o0[p] = vT * inv;
    o1[p] = vN * inv;
  }

  if (mode == 0) {
#pragma unroll
    for (int q = 0; q < 4; ++q) {
      f32x4 v0 = {o0[4*q], o0[4*q+1], o0[4*q+2], o0[4*q+3]};
      f32x4 v1 = {o1[4*q], o1[4*q+1], o1[4*q+2], o1[4*q+3]};
      *(f32x4*)(out_x1 + (size_t)chp * 147456 + i * 384 + j0 + 4 * q) = v0;
      *(f32x4*)(out_x1 + (size_t)(chp + 16) * 147456 + i * 384 + j0 + 4 * q) = v1;
    }
  } else {
    uint4_t u0, u1;
#pragma unroll
    for (int q = 0; q < 4; ++q) {
      u0[q] = f32_to_e4m3(o0[4*q]) | (f32_to_e4m3(o0[4*q+1]) << 8) |
              (f32_to_e4m3(o0[4*q+2]) << 16) | (f32_to_e4m3(o0[4*q+3]) << 24);
      u1[q] = f32_to_e4m3(o1[4*q]) | (f32_to_e4m3(o1[4*q+1]) << 8) |
              (f32_to_e4m3(o1[4*q+2]) << 16) | (f32_to_e4m3(o1[4*q+3]) << 24);
    }
    *(uint4_t*)(prevb + ((size_t)chp * 385 + i) * PREVB_STRIDE + j0) = u0;
    *(uint4_t*)(prevb + ((size_t)(chp + 16) * 385 + i) * PREVB_STRIDE + j0) = u1;
  }
}

// ---------------------------------------------------------------------------
// Pack x1 (fp32, cropped) into filtb fp8 MFMA-A layout; coalesced 8B writes.
// ---------------------------------------------------------------------------
__global__ __launch_bounds__(256) void pack_kernel(
    const float* __restrict__ x1, uchar_t* __restrict__ filtb)
{
  const int e = blockIdx.x * 256 + threadIdx.x;
  if (e >= 362 * 46 * 32) return;
  const int o = e & 31;
  const int q = e >> 5;
  const int xb = q % 46;
  const int rowr = q / 46 + 5;          // 5..366
  const int i = rowr + 6;               // 11..372
  const int j0 = 11 + xb * 8;
  const float* src = x1 + (size_t)o * 147456 + i * 384 + j0;
  uint_t w0 = 0, w1 = 0;
#pragma unroll
  for (int k = 0; k < 4; ++k) {
    w0 |= f32_to_e4m3((j0 + k     <= 372) ? src[k]     : 0.f) << (8 * k);
    w1 |= f32_to_e4m3((j0 + 4 + k <= 372) ? src[4 + k] : 0.f) << (8 * k);
  }
  uint2_t u = {w0, w1};
  *(uint2_t*)(filtb + (((size_t)(rowr * 48 + xb) * 32 + o) << 3)) = u;
}

// ---------------------------------------------------------------------------
// Stage 2: correlation via 32x32x16 fp8 MFMA.
//   out[o,c,dy,dx] = sum_{y,x} filt[o][y-dy_a][x] * prev[c][y+6*dy_b][x+dx]
//   M=192=(dy_a 6)x(o 32); N=96: n = dyb*24+dx (dx 0..22, 23=pad); K=(y, x).
// Block 384 thr = 6 waves, ONE channel; wave w = dy_a w, all 3 N-tiles of 32.
// A-operand row = y-w+5 is WAVE-UNIFORM -> one coalesced 8B load/lane/Kt.
// Operand map (32x32x16): m/n = lane&31, k = (lane>>5)*8 + j.
// C/D map: col = lane&31, row = (reg&3)+8*(reg>>2)+4*(lane>>5).
// Pair-buffered sB: each buffer holds TWO y-rows; 48-Kt K-loop per barrier;
// staging spread over waves 0-3 (208 tasks); rolling A prefetch.
// ---------------------------------------------------------------------------
__global__ __launch_bounds__(384, 4) void corr_kernel(
    const uchar_t* __restrict__ filtb, const uchar_t* __restrict__ prevb,
    float* __restrict__ x2)
{
  __shared__ uint_t sB[SB_TOT_B / 4];    // 55296 B

  const int tid = threadIdx.x;
  const int lane = tid & 63;
  const int w = tid >> 6;                // 0..5 = dy_a
  const int kg = lane >> 5;              // k-group 0..1
  const int nn = lane & 31;              // n (or o) within tile

  const int ch = blockIdx.x / NCHUNKS;         // 0..31
  const int chunk = blockIdx.x % NCHUNKS;      // 0..15; %8 == XCD
  const int y0 = (chunk * YMAX) / NCHUNKS;     // balanced 22-23 y-steps
  const int y1 = ((chunk + 1) * YMAX) / NCHUNKS;

  // Per-lane B-fragment byte offsets within a y-row image. All 8B-aligned.
  int boffB[3];
#pragma unroll
  for (int nt = 0; nt < 3; ++nt) {
    const int n = nt * 32 + nn;          // 0..95
    const int dyb = n / 24;
    const int dxr = n - 24 * dyb;
    const int dx = (dxr < 23) ? dxr : 22;      // pad lane reads valid data
    const int s = dx & 7;
    boffB[nt] = dyb * SB_DYB_B + s * SB_COPY_B + (dx >> 3) * 8 + kg * 8;
  }

  // Staging: 208 tasks = [srow 2][dyb 4][16B group g 26]; 24B src window each.
  // Spread over waves 0-3.
  const bool st_act = (tid < 208);
  const int tt = st_act ? tid : 0;
  const int srow = tt / 104;                   // 0..1 (y-row within pair)
  const int t104 = tt - 104 * srow;
  const int sdyb = t104 / 26;
  const int sg = t104 - 26 * sdyb;
  const uchar_t* srcbase =
      prevb + ((size_t)(ch * 385 + 6 * sdyb + srow)) * PREVB_STRIDE;
  const int dstoff = srow * (SB_ROW_B / 4) + sdyb * (SB_DYB_B / 4) + 4 * sg;

  uint_t st0 = 0, st1 = 0, st2 = 0, st3 = 0, st4 = 0, st5 = 0;

  // load prevb row (Y+srow+6*sdyb) for pair base step Y into st regs
  auto load_st = [&](int Y) {
    const uint_t* sw = (const uint_t*)(srcbase + (size_t)Y * PREVB_STRIDE) + 4 * sg;
    const uint4_t lo = *(const uint4_t*)(sw);
    const uint2_t hi = *(const uint2_t*)(sw + 4);
    st0 = lo.x; st1 = lo.y; st2 = lo.z; st3 = lo.w; st4 = hi.x; st5 = hi.y;
  };

  // expand st regs into 8 byte-shifted copies in pair-buffer buf
  auto write_shift = [&](int buf) {
    uint_t* dst = sB + buf * (SB_BUF_B / 4) + dstoff;
    const uint_t wd[6] = {st0, st1, st2, st3, st4, st5};
#pragma unroll
    for (int s = 0; s < 8; ++s) {
      const int off = s >> 2;
      const int b = (s & 3) * 8;
      uint4_t v;
      if (b == 0) {
        v = uint4_t{wd[off], wd[off + 1], wd[off + 2], wd[off + 3]};
      } else {
        v = uint4_t{(wd[off]     >> b) | (wd[off + 1] << (32 - b)),
                    (wd[off + 1] >> b) | (wd[off + 2] << (32 - b)),
                    (wd[off + 2] >> b) | (wd[off + 3] << (32 - b)),
                    (wd[off + 3] >> b) | (wd[off + 4] << (32 - b))};
      }
      *(uint4_t*)(dst + s * (SB_COPY_B / 4)) = v;
    }
  };

  f32x16 acc[3];
#pragma unroll
  for (int nt = 0; nt < 3; ++nt)
#pragma unroll
    for (int r = 0; r < 16; ++r) acc[nt][r] = 0.f;

  // Prologue: stage pair {y0,y0+1} into buf 0; preload {y0+2,y0+3} into regs.
  // (prevb has 385 rows; reads up to row y1+3+18 < 385 are in-range zeros.)
  if (st_act) {
    load_st(y0);
    write_shift(0);
    load_st(y0 + 2);
  }

  // A stream: rows contiguous in filtb (row stride 12288 = 24 Kt * 512B);
  // Af0/Af1 roll across sub-rows and iterations without re-warm.
  const uchar_t* aptr = filtb + (size_t)(y0 - w + 5) * 12288 + kg * 256 + nn * 8;
  long Af0 = *(const long*)(aptr);
  long Af1 = *(const long*)(aptr + 512);

  __syncthreads();                       // buf0 staged

  int Y = y0;
  int ib = 0;
  while (Y + 1 < y1) {
    // Stage pair {Y+2,Y+3} into the other buffer (its readers finished at
    // the end-of-previous-iteration barrier); then prefetch {Y+4,Y+5} regs.
    if (st_act) {
      if (Y + 2 < y1) write_shift(ib ^ 1);
      if (Y + 4 < y1) load_st(Y + 4);
    }

    const char* sBrd = (const char*)sB + ib * SB_BUF_B;

    // 48-Kt K-loop over the pair; A prefetched 2 deep (rolling, unclamped),
    // B 1 deep; sub-row switch at Kt=24 is a compile-time offset.
    long Af2, Bf[3], Bfn[3];
#pragma unroll
    for (int nt = 0; nt < 3; ++nt)
      Bf[nt] = *(const long*)(sBrd + boffB[nt]);

#pragma unroll
    for (int Kt = 0; Kt < 48; ++Kt) {
      Af2 = *(const long*)(aptr + ((Kt + 2) << 9));   // rolls into next rows
      const int Ktb = (Kt + 1 < 48) ? Kt + 1 : 47;
      const int ob = (Ktb < 24) ? (Ktb << 4) : (SB_ROW_B + ((Ktb - 24) << 4));
#pragma unroll
      for (int nt = 0; nt < 3; ++nt)
        Bfn[nt] = *(const long*)(sBrd + boffB[nt] + ob);
#pragma unroll
      for (int nt = 0; nt < 3; ++nt)
        acc[nt] = __builtin_amdgcn_mfma_f32_32x32x16_fp8_fp8(
            Af0, Bf[nt], acc[nt], 0, 0, 0);
      Af0 = Af1; Af1 = Af2;
#pragma unroll
      for (int nt = 0; nt < 3; ++nt) Bf[nt] = Bfn[nt];
    }
    aptr += 2 * 12288;                   // advanced 2 y-rows

    __syncthreads();                     // pair {Y+2,Y+3} visible; reads done
    Y += 2;
    ib ^= 1;
  }

  if (Y < y1) {
    // Odd tail: single row Y, staged as sub-row 0 of buf[ib].
    const char* sBrd = (const char*)sB + ib * SB_BUF_B;
    long Af2, Bf[3], Bfn[3];
#pragma unroll
    for (int nt = 0; nt < 3; ++nt)
      Bf[nt] = *(const long*)(sBrd + boffB[nt]);
#pragma unroll
    for (int Kt = 0; Kt < 24; ++Kt) {
      Af2 = *(const long*)(aptr + ((Kt + 2) << 9));
      const int Ktb = (Kt + 1 < 24) ? Kt + 1 : 23;
#pragma unroll
      for (int nt = 0; nt < 3; ++nt)
        Bfn[nt] = *(const long*)(sBrd + boffB[nt] + (Ktb << 4));
#pragma unroll
      for (int nt = 0; nt < 3; ++nt)
        acc[nt] = __builtin_amdgcn_mfma_f32_32x32x16_fp8_fp8(
            Af0, Bf[nt], acc[nt], 0, 0, 0);
      Af0 = Af1; Af1 = Af2;
#pragma unroll
      for (int nt = 0; nt < 3; ++nt) Bf[nt] = Bfn[nt];
    }
  }

  // Epilogue: scale partials, atomically accumulate into x2[o][c][dy][dx].
#pragma unroll
  for (int nt = 0; nt < 3; ++nt) {
    const int n = nt * 32 + nn;
    const int dyb = n / 24;
    const int dxr = n - 24 * dyb;
    if (dxr < 23) {
      const int dy = w + 6 * dyb;
      if (dy <= 22) {
#pragma unroll
        for (int r = 0; r < 16; ++r) {
          const int o = (r & 3) + 8 * (r >> 2) + 4 * kg;   // C/D row
          atomicAdd(&x2[((o * 32 + ch) * 23 + dy) * 23 + dxr],
                    acc[nt][r] * INV_AREA);
        }
      }
    }
  }
}

// ---------------------------------------------------------------------------
extern "C" void kernel_launch(void* const* d_in, const int* in_sizes, int n_in,
                              void* d_out, int out_size, void* d_ws, size_t ws_size,
                              hipStream_t stream)
{
  const float* x     = (const float*)d_in[0];   // [3][394][394]
  const float* xprev = (const float*)d_in[1];
  const float* ft    = (const float*)d_in[2];   // [16][3][11][11]
  const float* fn    = (const float*)d_in[3];   // [16][1][11][11]
  float* out = (float*)d_out;

  uchar_t* filtb = (uchar_t*)d_ws;
  uchar_t* prevb = filtb + FILTB_BYTES;
  float* fT2 = (float*)(prevb + PREVB_BYTES);

  // Zero packed buffers (zero padding) and the x2 accumulator.
  hipMemsetAsync(d_ws, 0, ZERO_BYTES, stream);
  hipMemsetAsync(out + X1_N, 0, (size_t)X2_N * sizeof(float), stream);

  prep_kernel<<<dim3((FT2_ELEMS + 255) / 256), 256, 0, stream>>>(ft, fn, fT2);
  feat_kernel<<<dim3(24, 48, 2), 128, 0, stream>>>(x, xprev, fT2, out, prevb);
  pack_kernel<<<dim3((362 * 46 * 32 + 255) / 256), 256, 0, stream>>>(out, filtb);
  corr_kernel<<<dim3(32 * NCHUNKS), 384, 0, stream>>>(filtb, prevb, out + X1_N);
}

// Round 4
// 303.363 us; speedup vs baseline: 1.1891x; 1.0718x over previous
//
#include <hip/hip_runtime.h>
#include <hip/hip_bf16.h>

// Net_22625887715641: fused conv-feats + channel-normalize + 32x32 normalized
// cross-correlation (23x23 shifts, 362x362 templates).
//
// R14 vs R13 (pair-buffer, 176us, occ 16%) / R11 (170us, MfmaUtil 40.6%):
//  Key R13 clue: solo block == 2x co-resident speed -> wall/MFMA ratio 2.5x
//  is wave-count invariant -> NOT latency; and no shared pipe saturated.
//  Culprit: 6-wave blocks place 2,2,1,1 waves on the 4 SIMDs -> matrix-pipe
//  load is 2:2:1:1. SIMD0/1 carry 10.7k pipe-cyc/y, SIMD2/3 half; aggregate
//  MfmaUtil ceiling 75% x SIMD0-eff ~60% = ~40% == measured. 6 doesn't
//  divide 4; 12 does.
//  - ONE 768-thread block = 12 waves = TWO channels: waves 0-5 ch=2p,
//    waves 6-11 ch=2p+1. Placement 3,3,3,3 -> balanced matrix pipes.
//  - Per-group R11 single-row double-buffered sB: 2 groups x 2 bufs x
//    13824B = 55296B static LDS. A (filtb) shared across groups (L1 hits).
//    Both groups same y-range -> block barrier stays convoy-free.
//  - Grid = 16 chpairs x 16 chunks = 256 blocks = exactly 1/CU, one round.
//    96 unified regs -> cap 5 waves/SIMD >= 3 needed (robust).
//  - Revert to R11 24-Kt single-row K-loop (R13 pair scheme: no gain).
//  - feat/pack/prep unchanged.

typedef unsigned short ushort_t;
typedef unsigned int uint_t;
typedef unsigned char uchar_t;
typedef __attribute__((ext_vector_type(4))) float f32x4;
typedef __attribute__((ext_vector_type(16))) float f32x16;
typedef __attribute__((ext_vector_type(4))) uint_t uint4_t;
typedef __attribute__((ext_vector_type(2))) uint_t uint2_t;

#define EPSF 2.2204460492503131e-16f
#define X1_N (32*384*384)
#define X2_N (32*32*23*23)

// filtb: fp8 [372 rows][48 xb][32 o][8 j]; row = yf+5 (data rows 5..366)
#define FILTB_BYTES (372*48*32*8)
// prevb: fp8 [32 c][385 rows][432 x]; data rows 0..383 cols 0..383; zeros else
#define PREVB_STRIDE 432
#define PREVB_BYTES (32*385*PREVB_STRIDE)
#define ZERO_BYTES ((size_t)FILTB_BYTES + PREVB_BYTES)
// fT2: fp32 [16 chp][45 rows][12] after prevb
#define FT2_ELEMS (16*45*12)

#define YMAX 367            // y-steps 0..366
#define NCHUNKS 16          // 16 chpairs x 16 chunks = 256 blocks = 1/CU
#define INV_AREA (1.0f/131044.0f)

// One y-row image in LDS: [dyb 4][copy 8][432]; copy stride 432
#define SB_COPY_B 432
#define SB_DYB_B  (8*SB_COPY_B)     // 3456
#define SB_ROW_B  (4*SB_DYB_B)      // 13824 B per y-row image
// total: 2 groups x 2 buffers x SB_ROW_B = 55296 B

// ---------------------------------------------------------------------------
// fp32 -> fp8 e4m3 (OCP), RNE, input assumed in [0, 448).
// ---------------------------------------------------------------------------
__device__ __forceinline__ uint_t f32_to_e4m3(float f) {
  if (f < 0.015625f)                         // subnormal: m * 2^-9
    return (uint_t)__float2int_rn(f * 512.0f);
  uint_t b = __builtin_bit_cast(uint_t, f);
  int e = (int)(b >> 23) - 127;
  uint_t m = b & 0x7FFFFFu;
  uint_t keep = m >> 20;
  uint_t rest = m & 0xFFFFFu;
  keep += (rest > 0x80000u) || (rest == 0x80000u && (keep & 1u));
  if (keep == 8u) { keep = 0u; e += 1; }
  if (e > 8) return 0x7Eu;                   // saturate 448
  return (uint_t)(((e + 7) << 3) | keep);
}

// ---------------------------------------------------------------------------
// Prep: pack filters to [chp][45][12] (rows 16B-aligned, b-contiguous).
// ---------------------------------------------------------------------------
__global__ void prep_kernel(const float* __restrict__ ft, const float* __restrict__ fn,
                            float* __restrict__ fT2)
{
  const int e = blockIdx.x * 256 + threadIdx.x;
  if (e < FT2_ELEMS) {
    const int chp = e / 540;
    const int rem = e - chp * 540;
    const int row = rem / 12;
    const int j = rem - row * 12;
    float v = 0.f;
    if (j < 11) {
      if (row < 33)      v = ft[chp * 363 + row * 11 + j];        // row = t*11+a
      else if (row < 44) v = fn[chp * 121 + (row - 33) * 11 + j]; // row-33 = a
    }
    fT2[e] = v;
  }
}

// ---------------------------------------------------------------------------
// Stage 1: thread = (ch-pair chp) x (16-px row). Block 128 = 8 rows x 16 chp.
// mode 0: x -> x1 (fp32). mode 1: xprev -> prevb (fp8 e4m3).
// ---------------------------------------------------------------------------
__global__ __launch_bounds__(128, 4) void feat_kernel(
    const float* __restrict__ xcur, const float* __restrict__ xprev,
    const float* __restrict__ fT2,
    float* __restrict__ out_x1, uchar_t* __restrict__ prevb)
{
  __shared__ float sPx[3 * 18 * 28];
  const int tid = threadIdx.x;
  const int chp = tid & 15;
  const int r = tid >> 4;              // 0..7
  const int j0 = blockIdx.x * 16;
  const int i0 = blockIdx.y * 8;
  const int i = i0 + r;
  const int mode = blockIdx.z;
  const float* __restrict__ xin = mode ? xprev : xcur;

  for (int e = tid; e < 3 * 18 * 26; e += 128) {
    const int t = e / 468;
    const int rem = e - t * 468;
    const int ri = rem / 26;
    const int ci = rem - ri * 26;
    sPx[(t * 18 + ri) * 28 + ci] = xin[((size_t)t * 394 + i0 + ri) * 394 + j0 + ci];
  }
  __syncthreads();

  const float* __restrict__ fbase = fT2 + chp * 540;

  float accT[16], accN[16];
#pragma unroll
  for (int p = 0; p < 16; ++p) { accT[p] = 0.f; accN[p] = 0.f; }

#pragma unroll
  for (int t = 0; t < 3; ++t) {
    for (int a = 0; a < 11; ++a) {
      const float* row = &sPx[(t * 18 + r + a) * 28];
      float wv[26];
#pragma unroll
      for (int k = 0; k < 6; ++k) {
        const f32x4 q = *(const f32x4*)(row + 4 * k);
        wv[4 * k + 0] = q[0]; wv[4 * k + 1] = q[1];
        wv[4 * k + 2] = q[2]; wv[4 * k + 3] = q[3];
      }
      wv[24] = row[24]; wv[25] = row[25];

      const float* fr = fbase + (t * 11 + a) * 12;
      const f32x4 fq0 = *(const f32x4*)(fr);
      const f32x4 fq1 = *(const f32x4*)(fr + 4);
      const f32x4 fq2 = *(const f32x4*)(fr + 8);
      float fv[12];
#pragma unroll
      for (int k = 0; k < 4; ++k) { fv[k] = fq0[k]; fv[4+k] = fq1[k]; fv[8+k] = fq2[k]; }
      float fv2[12];
      if (t == 2) {
        const float* fr2 = fbase + (33 + a) * 12;
        const f32x4 g0 = *(const f32x4*)(fr2);
        const f32x4 g1 = *(const f32x4*)(fr2 + 4);
        const f32x4 g2 = *(const f32x4*)(fr2 + 8);
#pragma unroll
        for (int k = 0; k < 4; ++k) { fv2[k] = g0[k]; fv2[4+k] = g1[k]; fv2[8+k] = g2[k]; }
      }

#pragma unroll
      for (int b = 0; b < 11; ++b) {
        const float fT = fv[b];
#pragma unroll
        for (int p = 0; p < 16; ++p) accT[p] = fmaf(wv[b + p], fT, accT[p]);
        if (t == 2) {
          const float fN = fv2[b];
#pragma unroll
          for (int p = 0; p < 16; ++p) accN[p] = fmaf(wv[b + p], fN, accN[p]);
        }
      }
    }
  }

  float o0[16], o1[16];
#pragma unroll
  for (int p = 0; p < 16; ++p) {
    const float vT = fmaxf(accT[p], 0.f) * 0.5f;   // temp: relu(conv)/2
    const float vN = fmaxf(accN[p], 0.f);
    float s = vT + vN;
    s += __shfl_xor(s, 1);  s += __shfl_xor(s, 2);
    s += __shfl_xor(s, 4);  s += __shfl_xor(s, 8);
    const float inv = 1.f / (s + EPSF);
    o0[p] = vT * inv;
    o1[p] = vN * inv;
  }

  if (mode == 0) {
#pragma unroll
    for (int q = 0; q < 4; ++q) {
      f32x4 v0 = {o0[4*q], o0[4*q+1], o0[4*q+2], o0[4*q+3]};
      f32x4 v1 = {o1[4*q], o1[4*q+1], o1[4*q+2], o1[4*q+3]};
      *(f32x4*)(out_x1 + (size_t)chp * 147456 + i * 384 + j0 + 4 * q) = v0;
      *(f32x4*)(out_x1 + (size_t)(chp + 16) * 147456 + i * 384 + j0 + 4 * q) = v1;
    }
  } else {
    uint4_t u0, u1;
#pragma unroll
    for (int q = 0; q < 4; ++q) {
      u0[q] = f32_to_e4m3(o0[4*q]) | (f32_to_e4m3(o0[4*q+1]) << 8) |
              (f32_to_e4m3(o0[4*q+2]) << 16) | (f32_to_e4m3(o0[4*q+3]) << 24);
      u1[q] = f32_to_e4m3(o1[4*q]) | (f32_to_e4m3(o1[4*q+1]) << 8) |
              (f32_to_e4m3(o1[4*q+2]) << 16) | (f32_to_e4m3(o1[4*q+3]) << 24);
    }
    *(uint4_t*)(prevb + ((size_t)chp * 385 + i) * PREVB_STRIDE + j0) = u0;
    *(uint4_t*)(prevb + ((size_t)(chp + 16) * 385 + i) * PREVB_STRIDE + j0) = u1;
  }
}

// ---------------------------------------------------------------------------
// Pack x1 (fp32, cropped) into filtb fp8 MFMA-A layout; coalesced 8B writes.
// ---------------------------------------------------------------------------
__global__ __launch_bounds__(256) void pack_kernel(
    const float* __restrict__ x1, uchar_t* __restrict__ filtb)
{
  const int e = blockIdx.x * 256 + threadIdx.x;
  if (e >= 362 * 46 * 32) return;
  const int o = e & 31;
  const int q = e >> 5;
  const int xb = q % 46;
  const int rowr = q / 46 + 5;          // 5..366
  const int i = rowr + 6;               // 11..372
  const int j0 = 11 + xb * 8;
  const float* src = x1 + (size_t)o * 147456 + i * 384 + j0;
  uint_t w0 = 0, w1 = 0;
#pragma unroll
  for (int k = 0; k < 4; ++k) {
    w0 |= f32_to_e4m3((j0 + k     <= 372) ? src[k]     : 0.f) << (8 * k);
    w1 |= f32_to_e4m3((j0 + 4 + k <= 372) ? src[4 + k] : 0.f) << (8 * k);
  }
  uint2_t u = {w0, w1};
  *(uint2_t*)(filtb + (((size_t)(rowr * 48 + xb) * 32 + o) << 3)) = u;
}

// ---------------------------------------------------------------------------
// Stage 2: correlation via 32x32x16 fp8 MFMA.
//   out[o,c,dy,dx] = sum_{y,x} filt[o][y-dy_a][x] * prev[c][y+6*dy_b][x+dx]
//   M=192=(dy_a 6)x(o 32); N=96: n = dyb*24+dx (dx 0..22, 23=pad); K=(y, x).
// Block 768 thr = 12 waves = TWO channels: waves 0-5 -> ch 2p (group 0),
// waves 6-11 -> ch 2p+1 (group 1). Wave placement 3,3,3,3 on SIMDs ->
// balanced matrix pipes (6-wave blocks were 2,2,1,1 -> 40% MfmaUtil cap).
// Within a group: wave w = dy_a w, all 3 N-tiles of 32; A-operand row
// = y-w+5 is WAVE-UNIFORM -> one coalesced 8B load/lane/Kt; filtb shared
// across groups (second group's A loads are L1 hits).
// Operand map (32x32x16): m/n = lane&31, k = (lane>>5)*8 + j.
// C/D map: col = lane&31, row = (reg&3)+8*(reg>>2)+4*(lane>>5).
// Per-group double-buffered single-row sB; one block barrier per y (both
// groups have identical y-ranges and per-y work -> no convoy asymmetry).
// ---------------------------------------------------------------------------
__global__ __launch_bounds__(768, 3) void corr_kernel(
    const uchar_t* __restrict__ filtb, const uchar_t* __restrict__ prevb,
    float* __restrict__ x2)
{
  __shared__ uint_t sB[2 * 2 * (SB_ROW_B / 4)];   // [group][buf][row] 55296 B

  const int tid = threadIdx.x;
  const int lane = tid & 63;
  const int wv = tid >> 6;               // 0..11
  const int cg = (wv >= 6) ? 1 : 0;      // channel sub-group
  const int w = wv - 6 * cg;             // 0..5 = dy_a
  const int kg = lane >> 5;              // k-group 0..1
  const int nn = lane & 31;              // n (or o) within tile

  const int chpair = blockIdx.x / NCHUNKS;     // 0..15
  const int chunk = blockIdx.x % NCHUNKS;      // 0..15; %8 == XCD
  const int ch = 2 * chpair + cg;              // 0..31
  const int y0 = (chunk * YMAX) / NCHUNKS;     // balanced 22-23 y-steps
  const int y1 = ((chunk + 1) * YMAX) / NCHUNKS;

  uint_t* const sBg = sB + cg * (2 * (SB_ROW_B / 4));   // group LDS base

  // Per-lane B-fragment byte offsets within a y-row image. All 8B-aligned.
  int boffB[3];
#pragma unroll
  for (int nt = 0; nt < 3; ++nt) {
    const int n = nt * 32 + nn;          // 0..95
    const int dyb = n / 24;
    const int dxr = n - 24 * dyb;
    const int dx = (dxr < 23) ? dxr : 22;      // pad lane reads valid data
    const int s = dx & 7;
    boffB[nt] = dyb * SB_DYB_B + s * SB_COPY_B + (dx >> 3) * 8 + kg * 8;
  }

  // Staging per group: 104 tasks (dyb = t/26, 16B group g = t%26); 24B src
  // window each; handled by the group's first ~2 waves.
  const int tl = tid - cg * 384;               // 0..383 within group
  const bool st_act = (tl < 104);
  const int sdyb = st_act ? (tl / 26) : 0;
  const int sg = tl - 26 * (st_act ? (tl / 26) : 0);
  const uchar_t* srcbase = prevb + ((size_t)(ch * 385 + 6 * sdyb)) * PREVB_STRIDE;
  const int dstoff = sdyb * (SB_DYB_B / 4) + 4 * sg;   // word offset in buffer

  uint_t st0 = 0, st1 = 0, st2 = 0, st3 = 0, st4 = 0, st5 = 0;

  // load prevb row for y-step yy into st regs
  auto load_st = [&](int yy) {
    const uint_t* sw = (const uint_t*)(srcbase + (size_t)yy * PREVB_STRIDE) + 4 * sg;
    const uint4_t lo = *(const uint4_t*)(sw);
    const uint2_t hi = *(const uint2_t*)(sw + 4);
    st0 = lo.x; st1 = lo.y; st2 = lo.z; st3 = lo.w; st4 = hi.x; st5 = hi.y;
  };

  // expand st regs into 8 byte-shifted copies in group buffer buf
  auto write_shift = [&](int buf) {
    uint_t* dst = sBg + buf * (SB_ROW_B / 4) + dstoff;
    const uint_t wd[6] = {st0, st1, st2, st3, st4, st5};
#pragma unroll
    for (int s = 0; s < 8; ++s) {
      const int off = s >> 2;
      const int b = (s & 3) * 8;
      uint4_t v;
      if (b == 0) {
        v = uint4_t{wd[off], wd[off + 1], wd[off + 2], wd[off + 3]};
      } else {
        v = uint4_t{(wd[off]     >> b) | (wd[off + 1] << (32 - b)),
                    (wd[off + 1] >> b) | (wd[off + 2] << (32 - b)),
                    (wd[off + 2] >> b) | (wd[off + 3] << (32 - b)),
                    (wd[off + 3] >> b) | (wd[off + 4] << (32 - b))};
      }
      *(uint4_t*)(dst + s * (SB_COPY_B / 4)) = v;
    }
  };

  f32x16 acc[3];
#pragma unroll
  for (int nt = 0; nt < 3; ++nt)
#pragma unroll
    for (int r = 0; r < 16; ++r) acc[nt][r] = 0.f;

  // Prologue: stage y0 into buf 0; preload y0+1 into regs.
  if (st_act) {
    load_st(y0);
    write_shift(0);
    if (y0 + 1 < y1) load_st(y0 + 1);
  }

  // A stream: rows contiguous in filtb (row stride 12288 = 24 Kt * 512B);
  // Af0/Af1 roll across y-iterations without re-warm.
  const uchar_t* aptr = filtb + (size_t)(y0 - w + 5) * 12288 + kg * 256 + nn * 8;
  long Af0 = *(const long*)(aptr);
  long Af1 = *(const long*)(aptr + 512);

  __syncthreads();                       // buf0 staged (both groups)

  for (int y = y0; y < y1; ++y) {
    const int pb = (y - y0) & 1;         // buffer being read this iteration

    // Stage y+1 into the other buffer (its readers finished at the end of
    // the previous iteration's barrier); then prefetch y+2 into regs —
    // a full K-loop of latency cover.
    if (st_act && y + 1 < y1) write_shift(pb ^ 1);
    if (st_act && y + 2 < y1) load_st(y + 2);

    const char* sBrd = (const char*)sBg + pb * SB_ROW_B;

    // K-loop: 24 Kt16 steps; A prefetched 2 deep (rolling, unclamped),
    // B 1 deep.
    long Af2, Bf[3], Bfn[3];
#pragma unroll
    for (int nt = 0; nt < 3; ++nt)
      Bf[nt] = *(const long*)(sBrd + boffB[nt]);

#pragma unroll
    for (int Kt = 0; Kt < 24; ++Kt) {
      Af2 = *(const long*)(aptr + ((Kt + 2) << 9));   // rolls into next row
      const int Ktb = (Kt + 1 < 24) ? Kt + 1 : 23;
#pragma unroll
      for (int nt = 0; nt < 3; ++nt)
        Bfn[nt] = *(const long*)(sBrd + boffB[nt] + (Ktb << 4));
#pragma unroll
      for (int nt = 0; nt < 3; ++nt)
        acc[nt] = __builtin_amdgcn_mfma_f32_32x32x16_fp8_fp8(
            Af0, Bf[nt], acc[nt], 0, 0, 0);
      Af0 = Af1; Af1 = Af2;
#pragma unroll
      for (int nt = 0; nt < 3; ++nt) Bf[nt] = Bfn[nt];
    }
    aptr += 12288;                       // next y: row += 1 (Af0/Af1 hold it)

    __syncthreads();                     // staging y+1 visible; reads done
  }

  // Epilogue: scale partials, atomically accumulate into x2[o][c][dy][dx].
#pragma unroll
  for (int nt = 0; nt < 3; ++nt) {
    const int n = nt * 32 + nn;
    const int dyb = n / 24;
    const int dxr = n - 24 * dyb;
    if (dxr < 23) {
      const int dy = w + 6 * dyb;
      if (dy <= 22) {
#pragma unroll
        for (int r = 0; r < 16; ++r) {
          const int o = (r & 3) + 8 * (r >> 2) + 4 * kg;   // C/D row
          atomicAdd(&x2[((o * 32 + ch) * 23 + dy) * 23 + dxr],
                    acc[nt][r] * INV_AREA);
        }
      }
    }
  }
}

// ---------------------------------------------------------------------------
extern "C" void kernel_launch(void* const* d_in, const int* in_sizes, int n_in,
                              void* d_out, int out_size, void* d_ws, size_t ws_size,
                              hipStream_t stream)
{
  const float* x     = (const float*)d_in[0];   // [3][394][394]
  const float* xprev = (const float*)d_in[1];
  const float* ft    = (const float*)d_in[2];   // [16][3][11][11]
  const float* fn    = (const float*)d_in[3];   // [16][1][11][11]
  float* out = (float*)d_out;

  uchar_t* filtb = (uchar_t*)d_ws;
  uchar_t* prevb = filtb + FILTB_BYTES;
  float* fT2 = (float*)(prevb + PREVB_BYTES);

  // Zero packed buffers (zero padding) and the x2 accumulator.
  hipMemsetAsync(d_ws, 0, ZERO_BYTES, stream);
  hipMemsetAsync(out + X1_N, 0, (size_t)X2_N * sizeof(float), stream);

  prep_kernel<<<dim3((FT2_ELEMS + 255) / 256), 256, 0, stream>>>(ft, fn, fT2);
  feat_kernel<<<dim3(24, 48, 2), 128, 0, stream>>>(x, xprev, fT2, out, prevb);
  pack_kernel<<<dim3((362 * 46 * 32 + 255) / 256), 256, 0, stream>>>(out, filtb);
  corr_kernel<<<dim3(16 * NCHUNKS), 768, 0, stream>>>(filtb, prevb, out + X1_N);
}

// Round 5
// 293.669 us; speedup vs baseline: 1.2283x; 1.0330x over previous
//
#include <hip/hip_runtime.h>
#include <hip/hip_bf16.h>

// Net_22625887715641: fused conv-feats + channel-normalize + 32x32 normalized
// cross-correlation (23x23 shifts, 362x362 templates).
//
// R15 vs R14 (corr 160us, MfmaUtil 43%, occ 30%):
//  R14 post-mortem: balance gave only +6%. Counter arithmetic: per wave,
//  one Kt round (~10 instr) per ~700 cyc -> 95% stall. Only long-latency
//  op in the K-loop: the global A-load from filtb (depth-2 prefetch ->
//  T = L/2 -> L ~ 1400 cyc = L3/HBM class). FETCH_SIZE ~ filtb refetched
//  per XCD per y-window confirms A-reads miss L2. All prior structural
//  fixes (occupancy/barriers/balance) never touched this.
//  - A-row LDS ring: block needs filt rows {y..y+5} (wave w reads row
//    y+5-w), advancing 1 row/y. Stage that row (12288B = 768 thr x 16B,
//    one b128 each) into an 8-slot ring (98304B), shared by BOTH channel
//    groups. Prologue stages 6 rows. Staged row has a full K-loop of
//    latency cover (vs 2 Kt rounds before).
//  - K-loop is now pure LDS: 1 A ds_read_b64 + 3 B ds_read_b64 + 3 MFMA
//    per Kt. No global ops -> no vmcnt exposure in the loop.
//  - LDS total 98304 + 55296 = 153600B -> dynamic LDS (
//    hipFuncSetAttribute MaxDynamicSharedMemorySize), 1 block/CU as now.
//  - feat/pack/prep unchanged.

typedef unsigned short ushort_t;
typedef unsigned int uint_t;
typedef unsigned char uchar_t;
typedef __attribute__((ext_vector_type(4))) float f32x4;
typedef __attribute__((ext_vector_type(16))) float f32x16;
typedef __attribute__((ext_vector_type(4))) uint_t uint4_t;
typedef __attribute__((ext_vector_type(2))) uint_t uint2_t;

#define EPSF 2.2204460492503131e-16f
#define X1_N (32*384*384)
#define X2_N (32*32*23*23)

// filtb: fp8 [372 rows][48 xb][32 o][8 j]; row = yf+5 (data rows 5..366)
#define FILTB_ROW_B 12288
#define FILTB_BYTES (372*48*32*8)
// prevb: fp8 [32 c][385 rows][432 x]; data rows 0..383 cols 0..383; zeros else
#define PREVB_STRIDE 432
#define PREVB_BYTES (32*385*PREVB_STRIDE)
#define ZERO_BYTES ((size_t)FILTB_BYTES + PREVB_BYTES)
// fT2: fp32 [16 chp][45 rows][12] after prevb
#define FT2_ELEMS (16*45*12)

#define YMAX 367            // y-steps 0..366
#define NCHUNKS 16          // 16 chpairs x 16 chunks = 256 blocks = 1/CU
#define INV_AREA (1.0f/131044.0f)

// One prev y-row image in LDS: [dyb 4][copy 8][432]; copy stride 432
#define SB_COPY_B 432
#define SB_DYB_B  (8*SB_COPY_B)     // 3456
#define SB_ROW_B  (4*SB_DYB_B)      // 13824 B per y-row image
#define SB_BYTES  (2*2*SB_ROW_B)    // [group][buf] = 55296 B

// A-ring: 8 slots x one filtb row
#define SA_BYTES  (8*FILTB_ROW_B)   // 98304 B
#define SMEM_TOTAL (SA_BYTES + SB_BYTES)   // 153600 B

// ---------------------------------------------------------------------------
// fp32 -> fp8 e4m3 (OCP), RNE, input assumed in [0, 448).
// ---------------------------------------------------------------------------
__device__ __forceinline__ uint_t f32_to_e4m3(float f) {
  if (f < 0.015625f)                         // subnormal: m * 2^-9
    return (uint_t)__float2int_rn(f * 512.0f);
  uint_t b = __builtin_bit_cast(uint_t, f);
  int e = (int)(b >> 23) - 127;
  uint_t m = b & 0x7FFFFFu;
  uint_t keep = m >> 20;
  uint_t rest = m & 0xFFFFFu;
  keep += (rest > 0x80000u) || (rest == 0x80000u && (keep & 1u));
  if (keep == 8u) { keep = 0u; e += 1; }
  if (e > 8) return 0x7Eu;                   // saturate 448
  return (uint_t)(((e + 7) << 3) | keep);
}

// ---------------------------------------------------------------------------
// Prep: pack filters to [chp][45][12] (rows 16B-aligned, b-contiguous).
// ---------------------------------------------------------------------------
__global__ void prep_kernel(const float* __restrict__ ft, const float* __restrict__ fn,
                            float* __restrict__ fT2)
{
  const int e = blockIdx.x * 256 + threadIdx.x;
  if (e < FT2_ELEMS) {
    const int chp = e / 540;
    const int rem = e - chp * 540;
    const int row = rem / 12;
    const int j = rem - row * 12;
    float v = 0.f;
    if (j < 11) {
      if (row < 33)      v = ft[chp * 363 + row * 11 + j];        // row = t*11+a
      else if (row < 44) v = fn[chp * 121 + (row - 33) * 11 + j]; // row-33 = a
    }
    fT2[e] = v;
  }
}

// ---------------------------------------------------------------------------
// Stage 1: thread = (ch-pair chp) x (16-px row). Block 128 = 8 rows x 16 chp.
// mode 0: x -> x1 (fp32). mode 1: xprev -> prevb (fp8 e4m3).
// ---------------------------------------------------------------------------
__global__ __launch_bounds__(128, 4) void feat_kernel(
    const float* __restrict__ xcur, const float* __restrict__ xprev,
    const float* __restrict__ fT2,
    float* __restrict__ out_x1, uchar_t* __restrict__ prevb)
{
  __shared__ float sPx[3 * 18 * 28];
  const int tid = threadIdx.x;
  const int chp = tid & 15;
  const int r = tid >> 4;              // 0..7
  const int j0 = blockIdx.x * 16;
  const int i0 = blockIdx.y * 8;
  const int i = i0 + r;
  const int mode = blockIdx.z;
  const float* __restrict__ xin = mode ? xprev : xcur;

  for (int e = tid; e < 3 * 18 * 26; e += 128) {
    const int t = e / 468;
    const int rem = e - t * 468;
    const int ri = rem / 26;
    const int ci = rem - ri * 26;
    sPx[(t * 18 + ri) * 28 + ci] = xin[((size_t)t * 394 + i0 + ri) * 394 + j0 + ci];
  }
  __syncthreads();

  const float* __restrict__ fbase = fT2 + chp * 540;

  float accT[16], accN[16];
#pragma unroll
  for (int p = 0; p < 16; ++p) { accT[p] = 0.f; accN[p] = 0.f; }

#pragma unroll
  for (int t = 0; t < 3; ++t) {
    for (int a = 0; a < 11; ++a) {
      const float* row = &sPx[(t * 18 + r + a) * 28];
      float wv[26];
#pragma unroll
      for (int k = 0; k < 6; ++k) {
        const f32x4 q = *(const f32x4*)(row + 4 * k);
        wv[4 * k + 0] = q[0]; wv[4 * k + 1] = q[1];
        wv[4 * k + 2] = q[2]; wv[4 * k + 3] = q[3];
      }
      wv[24] = row[24]; wv[25] = row[25];

      const float* fr = fbase + (t * 11 + a) * 12;
      const f32x4 fq0 = *(const f32x4*)(fr);
      const f32x4 fq1 = *(const f32x4*)(fr + 4);
      const f32x4 fq2 = *(const f32x4*)(fr + 8);
      float fv[12];
#pragma unroll
      for (int k = 0; k < 4; ++k) { fv[k] = fq0[k]; fv[4+k] = fq1[k]; fv[8+k] = fq2[k]; }
      float fv2[12];
      if (t == 2) {
        const float* fr2 = fbase + (33 + a) * 12;
        const f32x4 g0 = *(const f32x4*)(fr2);
        const f32x4 g1 = *(const f32x4*)(fr2 + 4);
        const f32x4 g2 = *(const f32x4*)(fr2 + 8);
#pragma unroll
        for (int k = 0; k < 4; ++k) { fv2[k] = g0[k]; fv2[4+k] = g1[k]; fv2[8+k] = g2[k]; }
      }

#pragma unroll
      for (int b = 0; b < 11; ++b) {
        const float fT = fv[b];
#pragma unroll
        for (int p = 0; p < 16; ++p) accT[p] = fmaf(wv[b + p], fT, accT[p]);
        if (t == 2) {
          const float fN = fv2[b];
#pragma unroll
          for (int p = 0; p < 16; ++p) accN[p] = fmaf(wv[b + p], fN, accN[p]);
        }
      }
    }
  }

  float o0[16], o1[16];
#pragma unroll
  for (int p = 0; p < 16; ++p) {
    const float vT = fmaxf(accT[p], 0.f) * 0.5f;   // temp: relu(conv)/2
    const float vN = fmaxf(accN[p], 0.f);
    float s = vT + vN;
    s += __shfl_xor(s, 1);  s += __shfl_xor(s, 2);
    s += __shfl_xor(s, 4);  s += __shfl_xor(s, 8);
    const float inv = 1.f / (s + EPSF);
    o0[p] = vT * inv;
    o1[p] = vN * inv;
  }

  if (mode == 0) {
#pragma unroll
    for (int q = 0; q < 4; ++q) {
      f32x4 v0 = {o0[4*q], o0[4*q+1], o0[4*q+2], o0[4*q+3]};
      f32x4 v1 = {o1[4*q], o1[4*q+1], o1[4*q+2], o1[4*q+3]};
      *(f32x4*)(out_x1 + (size_t)chp * 147456 + i * 384 + j0 + 4 * q) = v0;
      *(f32x4*)(out_x1 + (size_t)(chp + 16) * 147456 + i * 384 + j0 + 4 * q) = v1;
    }
  } else {
    uint4_t u0, u1;
#pragma unroll
    for (int q = 0; q < 4; ++q) {
      u0[q] = f32_to_e4m3(o0[4*q]) | (f32_to_e4m3(o0[4*q+1]) << 8) |
              (f32_to_e4m3(o0[4*q+2]) << 16) | (f32_to_e4m3(o0[4*q+3]) << 24);
      u1[q] = f32_to_e4m3(o1[4*q]) | (f32_to_e4m3(o1[4*q+1]) << 8) |
              (f32_to_e4m3(o1[4*q+2]) << 16) | (f32_to_e4m3(o1[4*q+3]) << 24);
    }
    *(uint4_t*)(prevb + ((size_t)chp * 385 + i) * PREVB_STRIDE + j0) = u0;
    *(uint4_t*)(prevb + ((size_t)(chp + 16) * 385 + i) * PREVB_STRIDE + j0) = u1;
  }
}

// ---------------------------------------------------------------------------
// Pack x1 (fp32, cropped) into filtb fp8 MFMA-A layout; coalesced 8B writes.
// ---------------------------------------------------------------------------
__global__ __launch_bounds__(256) void pack_kernel(
    const float* __restrict__ x1, uchar_t* __restrict__ filtb)
{
  const int e = blockIdx.x * 256 + threadIdx.x;
  if (e >= 362 * 46 * 32) return;
  const int o = e & 31;
  const int q = e >> 5;
  const int xb = q % 46;
  const int rowr = q / 46 + 5;          // 5..366
  const int i = rowr + 6;               // 11..372
  const int j0 = 11 + xb * 8;
  const float* src = x1 + (size_t)o * 147456 + i * 384 + j0;
  uint_t w0 = 0, w1 = 0;
#pragma unroll
  for (int k = 0; k < 4; ++k) {
    w0 |= f32_to_e4m3((j0 + k     <= 372) ? src[k]     : 0.f) << (8 * k);
    w1 |= f32_to_e4m3((j0 + 4 + k <= 372) ? src[4 + k] : 0.f) << (8 * k);
  }
  uint2_t u = {w0, w1};
  *(uint2_t*)(filtb + (((size_t)(rowr * 48 + xb) * 32 + o) << 3)) = u;
}

// ---------------------------------------------------------------------------
// Stage 2: correlation via 32x32x16 fp8 MFMA.
//   out[o,c,dy,dx] = sum_{y,x} filt[o][y-dy_a][x] * prev[c][y+6*dy_b][x+dx]
//   M=192=(dy_a 6)x(o 32); N=96: n = dyb*24+dx (dx 0..22, 23=pad); K=(y, x).
// Block 768 thr = 12 waves = TWO channels: waves 0-5 -> ch 2p (group 0),
// waves 6-11 -> ch 2p+1 (group 1); placement 3,3,3,3 -> balanced pipes.
// A: filt rows in an 8-slot LDS ring shared by both groups; wave w reads
// ring slot (y+5-w)&7. One new row (12288B) staged per y by all 768 thr
// (16B each), written AFTER the K-loop, visible after the barrier.
// B: per-group double-buffered single-row image (8 byte-shifted copies).
// K-loop: pure LDS (1 A + 3 B ds_read_b64 + 3 MFMA per Kt), no global ops.
// Operand map (32x32x16): m/n = lane&31, k = (lane>>5)*8 + j.
// C/D map: col = lane&31, row = (reg&3)+8*(reg>>2)+4*(lane>>5).
// ---------------------------------------------------------------------------
__global__ __launch_bounds__(768, 3) void corr_kernel(
    const uchar_t* __restrict__ filtb, const uchar_t* __restrict__ prevb,
    float* __restrict__ x2)
{
  extern __shared__ uchar_t smem[];          // [A ring 98304][B 55296]

  const int tid = threadIdx.x;
  const int lane = tid & 63;
  const int wv = tid >> 6;               // 0..11
  const int cg = (wv >= 6) ? 1 : 0;      // channel sub-group
  const int w = wv - 6 * cg;             // 0..5 = dy_a
  const int kg = lane >> 5;              // k-group 0..1
  const int nn = lane & 31;              // n (or o) within tile

  const int chpair = blockIdx.x / NCHUNKS;     // 0..15
  const int chunk = blockIdx.x % NCHUNKS;      // 0..15; %8 == XCD
  const int ch = 2 * chpair + cg;              // 0..31
  const int y0 = (chunk * YMAX) / NCHUNKS;     // balanced 22-23 y-steps
  const int y1 = ((chunk + 1) * YMAX) / NCHUNKS;

  uint_t* const sBg = (uint_t*)(smem + SA_BYTES) + cg * (2 * (SB_ROW_B / 4));

  // Per-lane B-fragment byte offsets within a y-row image. All 8B-aligned.
  int boffB[3];
#pragma unroll
  for (int nt = 0; nt < 3; ++nt) {
    const int n = nt * 32 + nn;          // 0..95
    const int dyb = n / 24;
    const int dxr = n - 24 * dyb;
    const int dx = (dxr < 23) ? dxr : 22;      // pad lane reads valid data
    const int s = dx & 7;
    boffB[nt] = dyb * SB_DYB_B + s * SB_COPY_B + (dx >> 3) * 8 + kg * 8;
  }

  // B staging per group: 104 tasks (dyb = t/26, 16B group g = t%26).
  const int tl = tid - cg * 384;               // 0..383 within group
  const bool st_act = (tl < 104);
  const int sdyb = st_act ? (tl / 26) : 0;
  const int sg = tl - 26 * (st_act ? (tl / 26) : 0);
  const uchar_t* srcbase = prevb + ((size_t)(ch * 385 + 6 * sdyb)) * PREVB_STRIDE;
  const int dstoff = sdyb * (SB_DYB_B / 4) + 4 * sg;   // word offset in buffer

  uint_t st0 = 0, st1 = 0, st2 = 0, st3 = 0, st4 = 0, st5 = 0;

  auto load_st = [&](int yy) {
    const uint_t* sw = (const uint_t*)(srcbase + (size_t)yy * PREVB_STRIDE) + 4 * sg;
    const uint4_t lo = *(const uint4_t*)(sw);
    const uint2_t hi = *(const uint2_t*)(sw + 4);
    st0 = lo.x; st1 = lo.y; st2 = lo.z; st3 = lo.w; st4 = hi.x; st5 = hi.y;
  };

  auto write_shift = [&](int buf) {
    uint_t* dst = sBg + buf * (SB_ROW_B / 4) + dstoff;
    const uint_t wd[6] = {st0, st1, st2, st3, st4, st5};
#pragma unroll
    for (int s = 0; s < 8; ++s) {
      const int off = s >> 2;
      const int b = (s & 3) * 8;
      uint4_t v;
      if (b == 0) {
        v = uint4_t{wd[off], wd[off + 1], wd[off + 2], wd[off + 3]};
      } else {
        v = uint4_t{(wd[off]     >> b) | (wd[off + 1] << (32 - b)),
                    (wd[off + 1] >> b) | (wd[off + 2] << (32 - b)),
                    (wd[off + 2] >> b) | (wd[off + 3] << (32 - b)),
                    (wd[off + 3] >> b) | (wd[off + 4] << (32 - b))};
      }
      *(uint4_t*)(dst + s * (SB_COPY_B / 4)) = v;
    }
  };

  f32x16 acc[3];
#pragma unroll
  for (int nt = 0; nt < 3; ++nt)
#pragma unroll
    for (int r = 0; r < 16; ++r) acc[nt][r] = 0.f;

  // ---- Prologue ----
  // A: stage 6 filt rows y0..y0+5 into ring slots (row&7); 768 thr x 16B.
  {
    uint4_t pv[6];
#pragma unroll
    for (int r6 = 0; r6 < 6; ++r6)
      pv[r6] = *(const uint4_t*)(filtb + (size_t)(y0 + r6) * FILTB_ROW_B + tid * 16);
#pragma unroll
    for (int r6 = 0; r6 < 6; ++r6)
      *(uint4_t*)(smem + ((y0 + r6) & 7) * FILTB_ROW_B + tid * 16) = pv[r6];
  }
  // B: stage y0 into buf 0; preload y0+1 into regs.
  if (st_act) {
    load_st(y0);
    write_shift(0);
    if (y0 + 1 < y1) load_st(y0 + 1);
  }

  __syncthreads();                       // A rows y0..y0+5 + B buf0 staged

  for (int y = y0; y < y1; ++y) {
    const int pb = (y - y0) & 1;         // B buffer being read this iteration

    // A: issue global load of filt row y+6 (used from iteration y+1 on;
    // written to LDS after this K-loop -> a full K-loop of latency cover).
    const bool a_act = (y + 6 <= y1 + 4);
    uint4_t aval;
    if (a_act)
      aval = *(const uint4_t*)(filtb + (size_t)(y + 6) * FILTB_ROW_B + tid * 16);

    // B: stage y+1 into the other buffer; prefetch y+2 into regs.
    if (st_act && y + 1 < y1) write_shift(pb ^ 1);
    if (st_act && y + 2 < y1) load_st(y + 2);

    const char* sBrd = (const char*)sBg + pb * SB_ROW_B;
    const char* aRow = (const char*)smem +
        ((y + 5 - w) & 7) * FILTB_ROW_B + kg * 256 + nn * 8;

    // K-loop: pure LDS; A and B prefetched 1 Kt deep.
    long Af, Afn, Bf[3], Bfn[3];
    Af = *(const long*)(aRow);
#pragma unroll
    for (int nt = 0; nt < 3; ++nt)
      Bf[nt] = *(const long*)(sBrd + boffB[nt]);

#pragma unroll
    for (int Kt = 0; Kt < 24; ++Kt) {
      const int Ktn = (Kt + 1 < 24) ? Kt + 1 : 23;
      Afn = *(const long*)(aRow + (Ktn << 9));
#pragma unroll
      for (int nt = 0; nt < 3; ++nt)
        Bfn[nt] = *(const long*)(sBrd + boffB[nt] + (Ktn << 4));
#pragma unroll
      for (int nt = 0; nt < 3; ++nt)
        acc[nt] = __builtin_amdgcn_mfma_f32_32x32x16_fp8_fp8(
            Af, Bf[nt], acc[nt], 0, 0, 0);
      Af = Afn;
#pragma unroll
      for (int nt = 0; nt < 3; ++nt) Bf[nt] = Bfn[nt];
    }

    // A: write staged row into ring slot (y+6)&7 — disjoint from slots
    // {y..y+5}&7 still being read by other waves; safe without a barrier.
    if (a_act)
      *(uint4_t*)(smem + ((y + 6) & 7) * FILTB_ROW_B + tid * 16) = aval;

    __syncthreads();                     // A row y+6 + B buf y+1 visible
  }

  // Epilogue: scale partials, atomically accumulate into x2[o][c][dy][dx].
#pragma unroll
  for (int nt = 0; nt < 3; ++nt) {
    const int n = nt * 32 + nn;
    const int dyb = n / 24;
    const int dxr = n - 24 * dyb;
    if (dxr < 23) {
      const int dy = w + 6 * dyb;
      if (dy <= 22) {
#pragma unroll
        for (int r = 0; r < 16; ++r) {
          const int o = (r & 3) + 8 * (r >> 2) + 4 * kg;   // C/D row
          atomicAdd(&x2[((o * 32 + ch) * 23 + dy) * 23 + dxr],
                    acc[nt][r] * INV_AREA);
        }
      }
    }
  }
}

// ---------------------------------------------------------------------------
extern "C" void kernel_launch(void* const* d_in, const int* in_sizes, int n_in,
                              void* d_out, int out_size, void* d_ws, size_t ws_size,
                              hipStream_t stream)
{
  const float* x     = (const float*)d_in[0];   // [3][394][394]
  const float* xprev = (const float*)d_in[1];
  const float* ft    = (const float*)d_in[2];   // [16][3][11][11]
  const float* fn    = (const float*)d_in[3];   // [16][1][11][11]
  float* out = (float*)d_out;

  uchar_t* filtb = (uchar_t*)d_ws;
  uchar_t* prevb = filtb + FILTB_BYTES;
  float* fT2 = (float*)(prevb + PREVB_BYTES);

  static bool attr_set = false;
  if (!attr_set) {
    (void)hipFuncSetAttribute((const void*)corr_kernel,
        hipFuncAttributeMaxDynamicSharedMemorySize, SMEM_TOTAL);
    attr_set = true;
  }

  // Zero packed buffers (zero padding) and the x2 accumulator.
  hipMemsetAsync(d_ws, 0, ZERO_BYTES, stream);
  hipMemsetAsync(out + X1_N, 0, (size_t)X2_N * sizeof(float), stream);

  prep_kernel<<<dim3((FT2_ELEMS + 255) / 256), 256, 0, stream>>>(ft, fn, fT2);
  feat_kernel<<<dim3(24, 48, 2), 128, 0, stream>>>(x, xprev, fT2, out, prevb);
  pack_kernel<<<dim3((362 * 46 * 32 + 255) / 256), 256, 0, stream>>>(out, filtb);
  corr_kernel<<<dim3(16 * NCHUNKS), 768, SMEM_TOTAL, stream>>>(
      filtb, prevb, out + X1_N);
}